// Round 3
// baseline (992.401 us; speedup 1.0000x reference)
//
#include <hip/hip_runtime.h>

#define BATCH 16
#define HEADS 8
#define WORD  128
#define CELLS 16384
#define CTRL  1072      // HEADS*(WORD+6)
#define CB    256       // cells per block in read kernel

__device__ __forceinline__ float softplusf(float x) {
  return (x > 20.f) ? x : log1pf(expf(x));
}

// OP: 0 = sum, 1 = max.  scratch needs >= 16 floats; it is the big LDS buffer,
// safe to reuse because of the leading/trailing barriers.
template<int OP>
__device__ __forceinline__ float block_reduce(float v, float* scratch) {
  #pragma unroll
  for (int o = 32; o > 0; o >>= 1) {
    float u = __shfl_xor(v, o, 64);
    v = OP ? fmaxf(v, u) : (v + u);
  }
  const int t = threadIdx.x;
  __syncthreads();                       // scratch may still be in use by caller
  if ((t & 63) == 0) scratch[t >> 6] = v;
  __syncthreads();
  if (t < 64) {
    v = (t < 16) ? scratch[t] : (OP ? -3.4e38f : 0.f);
    #pragma unroll
    for (int o = 8; o > 0; o >>= 1) {
      float u = __shfl_xor(v, o, 64);
      v = OP ? fmaxf(v, u) : (v + u);
    }
    if (t == 0) scratch[0] = v;
  }
  __syncthreads();
  v = scratch[0];
  __syncthreads();                       // caller may immediately reuse scratch
  return v;
}

// ---------------- Kernel 1: cosine-similarity scores ----------------
// grid (CELLS/256, BATCH), block 256. One thread per cell.
// INSTRUMENTED: runtime `iters` loop with laundered pointers so each
// iteration re-does identical global loads + stores (idempotent).
__global__ __launch_bounds__(256)
void scores_kernel(const float* __restrict__ mem,
                   const float* __restrict__ ctrl,
                   float* __restrict__ scores, int iters) {
  const int b = blockIdx.y;
  const int c = blockIdx.x * 256 + threadIdx.x;
  const int t = threadIdx.x;

  __shared__ float kk[HEADS * WORD];   // tanh(keys), [h][w]
  __shared__ float kn[HEADS];          // ||key_h||

  for (int i = t; i < HEADS * WORD; i += 256)
    kk[i] = tanhf(ctrl[b * CTRL + i]);
  __syncthreads();
  if (t < HEADS) {
    float s = 0.f;
    for (int w = 0; w < WORD; ++w) { float v = kk[t * WORD + w]; s += v * v; }
    kn[t] = sqrtf(s);
  }
  __syncthreads();

  for (int it = 0; it < iters; ++it) {
    // launder the pointers: compiler must treat each iteration's loads and
    // stores as new (prevents hoist/CSE/dead-store-elim of the repeat loop)
    const float* mbase = mem;
    float* sbase = scores;
    asm volatile("" : "+v"(mbase), "+v"(sbase));

    float dot[HEADS];
    #pragma unroll
    for (int h = 0; h < HEADS; ++h) dot[h] = 0.f;
    float nm = 0.f;

    const float4* mrow = (const float4*)&mbase[((size_t)b * CELLS + c) * WORD];
    const float4* k4   = (const float4*)kk;
    for (int w4 = 0; w4 < WORD / 4; ++w4) {
      float4 m = mrow[w4];
      nm = fmaf(m.x, m.x, fmaf(m.y, m.y, fmaf(m.z, m.z, fmaf(m.w, m.w, nm))));
      #pragma unroll
      for (int h = 0; h < HEADS; ++h) {
        float4 k = k4[h * (WORD / 4) + w4];   // uniform -> LDS broadcast
        dot[h] = fmaf(m.x, k.x, fmaf(m.y, k.y, fmaf(m.z, k.z, fmaf(m.w, k.w, dot[h]))));
      }
    }
    nm = sqrtf(nm);
    #pragma unroll
    for (int h = 0; h < HEADS; ++h)
      sbase[((size_t)(b * HEADS + h)) * CELLS + c] = dot[h] / (kn[h] * nm + 1e-8f);
  }
}

// ---------------- Kernel 2: softmax / interp / shift / sharpen ----------------
// grid (BATCH*HEADS), block 1024, 64 KB LDS (exactly).  UNCHANGED from round 1.
__global__ __launch_bounds__(1024)
void weights_kernel(const float* __restrict__ scores,
                    const float* __restrict__ ctrl,
                    const float* __restrict__ bias,
                    float* __restrict__ rd) {
  const int bh = blockIdx.x;
  const int b = bh >> 3, h = bh & 7;
  const int t = threadIdx.x;

  __shared__ float buf[CELLS];   // 64 KB: reduction scratch, then w_interp row

  const float* cb = ctrl + b * CTRL;
  const float beta  = softplusf(cb[1024 + h]);
  const float gate  = 1.f / (1.f + expf(-cb[1032 + h]));
  float s0 = cb[1040 + h * 3 + 0];
  float s1 = cb[1040 + h * 3 + 1];
  float s2 = cb[1040 + h * 3 + 2];
  {
    float sm = fmaxf(s0, fmaxf(s1, s2));
    float e0 = expf(s0 - sm), e1 = expf(s1 - sm), e2 = expf(s2 - sm);
    float inv = 1.f / (e0 + e1 + e2);
    s0 = e0 * inv; s1 = e1 * inv; s2 = e2 * inv;
  }
  const float gamma = 1.f + softplusf(cb[1064 + h]);

  // --- content softmax: x = scores*beta ---
  float x[16];
  const float* srow = scores + (size_t)bh * CELLS;
  #pragma unroll
  for (int i = 0; i < 16; ++i) x[i] = srow[t + i * 1024] * beta;
  float mx = x[0];
  #pragma unroll
  for (int i = 1; i < 16; ++i) mx = fmaxf(mx, x[i]);
  mx = block_reduce<1>(mx, buf);
  float se = 0.f;
  #pragma unroll
  for (int i = 0; i < 16; ++i) { x[i] = expf(x[i] - mx); se += x[i]; }
  se = block_reduce<0>(se, buf);

  // --- prev-weights softmax of bias row (same for all b) ---
  float y[16];
  const float* brow = bias + (size_t)h * CELLS;
  #pragma unroll
  for (int i = 0; i < 16; ++i) y[i] = brow[t + i * 1024];
  float mb = y[0];
  #pragma unroll
  for (int i = 1; i < 16; ++i) mb = fmaxf(mb, y[i]);
  mb = block_reduce<1>(mb, buf);
  float sb = 0.f;
  #pragma unroll
  for (int i = 0; i < 16; ++i) { y[i] = expf(y[i] - mb); sb += y[i]; }
  sb = block_reduce<0>(sb, buf);

  // --- interpolate into LDS ---
  const float a1 = gate / se;
  const float a2 = (1.f - gate) / sb;
  #pragma unroll
  for (int i = 0; i < 16; ++i)
    buf[t + i * 1024] = a1 * x[i] + a2 * y[i];
  __syncthreads();

  // --- circular shift + sharpen ---
  float sh[16]; float ss = 0.f;
  #pragma unroll
  for (int i = 0; i < 16; ++i) {
    int c = t + i * 1024;
    float wm = buf[(c + CELLS - 1) & (CELLS - 1)];
    float w0 = buf[c];
    float wp = buf[(c + 1) & (CELLS - 1)];
    float ws = fmaf(s0, wm, fmaf(s1, w0, s2 * wp));
    float p = powf(ws, gamma);
    sh[i] = p; ss += p;
  }
  // block_reduce has a leading barrier, so neighbor reads are done before reuse
  ss = block_reduce<0>(ss, buf);
  const float inv = 1.f / (ss + 1e-8f);
  float* rrow = rd + (size_t)bh * CELLS;
  #pragma unroll
  for (int i = 0; i < 16; ++i) rrow[t + i * 1024] = sh[i] * inv;
}

// ---------------- Kernel 3: weighted read ----------------
// grid (CELLS/CB, BATCH), block 256.  UNCHANGED from round 1.
__global__ __launch_bounds__(256)
void read_kernel(const float* __restrict__ mem,
                 const float* __restrict__ rd,
                 float* __restrict__ out) {
  const int b  = blockIdx.y;
  const int c0 = blockIdx.x * CB;
  const int t  = threadIdx.x;

  __shared__ float rds[HEADS][CB];           // 8 KB
  __shared__ float red[8][HEADS * WORD];     // 32 KB, [cc][h*128+w]

  for (int i = t; i < HEADS * CB; i += 256)
    rds[i >> 8][i & 255] = rd[((size_t)b * HEADS + (i >> 8)) * CELLS + c0 + (i & 255)];
  __syncthreads();

  const int w4 = (t & 31) * 4;   // word offset (float4)
  const int cc = t >> 5;         // 8-way split over cells
  float4 acc[HEADS];
  #pragma unroll
  for (int h = 0; h < HEADS; ++h) acc[h] = make_float4(0.f, 0.f, 0.f, 0.f);

  for (int c = cc; c < CB; c += 8) {
    float4 m = *(const float4*)&mem[((size_t)b * CELLS + c0 + c) * WORD + w4];
    #pragma unroll
    for (int h = 0; h < HEADS; ++h) {
      float r = rds[h][c];                   // 2 addrs/wave -> broadcast
      acc[h].x = fmaf(r, m.x, acc[h].x);
      acc[h].y = fmaf(r, m.y, acc[h].y);
      acc[h].z = fmaf(r, m.z, acc[h].z);
      acc[h].w = fmaf(r, m.w, acc[h].w);
    }
  }

  #pragma unroll
  for (int h = 0; h < HEADS; ++h)
    *(float4*)&red[cc][h * WORD + w4] = acc[h];
  __syncthreads();

  // 1024 outputs, 256 threads -> one float4 each, summed over cc
  float4 s = *(float4*)&red[0][t * 4];
  #pragma unroll
  for (int c2 = 1; c2 < 8; ++c2) {
    float4 v = *(float4*)&red[c2][t * 4];
    s.x += v.x; s.y += v.y; s.z += v.z; s.w += v.w;
  }
  const int h = t >> 5;            // (t*4)/128
  const int w = (t * 4) & 127;
  float* o = &out[((size_t)b * HEADS + h) * WORD + w];
  atomicAdd(o + 0, s.x);
  atomicAdd(o + 1, s.y);
  atomicAdd(o + 2, s.z);
  atomicAdd(o + 3, s.w);
}

extern "C" void kernel_launch(void* const* d_in, const int* in_sizes, int n_in,
                              void* d_out, int out_size, void* d_ws, size_t ws_size,
                              hipStream_t stream) {
  const float* mem  = (const float*)d_in[0];
  const float* ctrl = (const float*)d_in[1];
  const float* bias = (const float*)d_in[2];
  float* out    = (float*)d_out;
  float* scores = (float*)d_ws;                              // 8 MB
  float* rd     = scores + (size_t)BATCH * HEADS * CELLS;    // 8 MB (needs 16 MB ws)

  hipMemsetAsync(d_out, 0, sizeof(float) * BATCH * HEADS * WORD, stream);

  // MEASUREMENT ROUND: scores_kernel amplified x10 (idempotent), k2/k3 unchanged.
  // k1_per_unit = (dur_us - 271) / 9
  scores_kernel<<<dim3(CELLS / 256, BATCH), 256, 0, stream>>>(mem, ctrl, scores, 10);
  weights_kernel<<<dim3(BATCH * HEADS), 1024, 0, stream>>>(scores, ctrl, bias, rd);
  read_kernel<<<dim3(CELLS / CB, BATCH), 256, 0, stream>>>(mem, rd, out);
}

// Round 4
// 722.714 us; speedup vs baseline: 1.3732x; 1.3732x over previous
//
#include <hip/hip_runtime.h>

#define BATCH 16
#define HEADS 8
#define WORD  128
#define CELLS 16384
#define CTRL  1072      // HEADS*(WORD+6)
#define CB    256       // cells per block in read kernel

__device__ __forceinline__ float softplusf(float x) {
  return (x > 20.f) ? x : log1pf(expf(x));
}

// OP: 0 = sum, 1 = max.  scratch needs >= 16 floats; it is the big LDS buffer,
// safe to reuse because of the leading/trailing barriers.
template<int OP>
__device__ __forceinline__ float block_reduce(float v, float* scratch) {
  #pragma unroll
  for (int o = 32; o > 0; o >>= 1) {
    float u = __shfl_xor(v, o, 64);
    v = OP ? fmaxf(v, u) : (v + u);
  }
  const int t = threadIdx.x;
  __syncthreads();                       // scratch may still be in use by caller
  if ((t & 63) == 0) scratch[t >> 6] = v;
  __syncthreads();
  if (t < 64) {
    v = (t < 16) ? scratch[t] : (OP ? -3.4e38f : 0.f);
    #pragma unroll
    for (int o = 8; o > 0; o >>= 1) {
      float u = __shfl_xor(v, o, 64);
      v = OP ? fmaxf(v, u) : (v + u);
    }
    if (t == 0) scratch[0] = v;
  }
  __syncthreads();
  v = scratch[0];
  __syncthreads();                       // caller may immediately reuse scratch
  return v;
}

// ---------------- Kernel 1: cosine-similarity scores (REWRITTEN) ----------------
// Wave-cooperative: 64 lanes read TWO full 512B rows per step (1KB contiguous).
// Lane l: row = base + (l>>5), float4 column = l&31. Dots/norm reduced via
// 5-step shfl_xor butterfly within each 32-lane half. Keys hoisted to VGPRs.
// grid (CELLS/128, BATCH), block 256 (4 waves x 32 cells each).
__global__ __launch_bounds__(256)
void scores_kernel(const float* __restrict__ mem,
                   const float* __restrict__ ctrl,
                   float* __restrict__ scores) {
  const int b  = blockIdx.y;
  const int t  = threadIdx.x;
  const int wv = t >> 6;        // wave 0..3
  const int l  = t & 63;
  const int half = l >> 5;      // which of the 2 rows this lane serves
  const int li   = l & 31;      // float4 column within the row

  __shared__ float kk[HEADS * WORD];   // tanh(keys)
  __shared__ float kn[HEADS];          // ||key_h||

  for (int i = t; i < HEADS * WORD; i += 256)
    kk[i] = tanhf(ctrl[b * CTRL + i]);
  __syncthreads();
  if (t < HEADS) {
    float s = 0.f;
    for (int w = 0; w < WORD; ++w) { float v = kk[t * WORD + w]; s += v * v; }
    kn[t] = sqrtf(s);
  }
  __syncthreads();

  // hoist key fragments: lane li needs kk[h][li*4 .. li*4+3] for all h
  float4 kreg[HEADS];
  #pragma unroll
  for (int h = 0; h < HEADS; ++h)
    kreg[h] = *(const float4*)&kk[h * WORD + li * 4];
  const float knl = kn[li & 7];   // only meaningful for li<8 (writer lanes)

  const int c0 = blockIdx.x * 128 + wv * 32;
  const float4* mb = (const float4*)(mem + (size_t)b * CELLS * WORD);

  for (int s = 0; s < 16; ++s) {
    const int row = c0 + 2 * s + half;
    float4 m = mb[(size_t)row * 32 + li];

    float nmv = fmaf(m.x, m.x, fmaf(m.y, m.y, fmaf(m.z, m.z, m.w * m.w)));
    float d[HEADS];
    #pragma unroll
    for (int h = 0; h < HEADS; ++h)
      d[h] = fmaf(m.x, kreg[h].x, fmaf(m.y, kreg[h].y,
             fmaf(m.z, kreg[h].z, m.w * kreg[h].w)));

    // butterfly sum over the 32 lanes of each half (masks <=16 stay in-half)
    #pragma unroll
    for (int off = 1; off <= 16; off <<= 1) {
      #pragma unroll
      for (int h = 0; h < HEADS; ++h) d[h] += __shfl_xor(d[h], off);
      nmv += __shfl_xor(nmv, off);
    }

    if (li < HEADS) {
      const float nmr = sqrtf(nmv);
      float dsel = d[0];
      #pragma unroll
      for (int h = 1; h < HEADS; ++h) dsel = (li == h) ? d[h] : dsel;
      scores[((size_t)(b * HEADS + li)) * CELLS + row] = dsel / (knl * nmr + 1e-8f);
    }
  }
}

// ---------------- Kernel 2: softmax / interp / shift / sharpen ----------------
// grid (BATCH*HEADS), block 1024, 64 KB LDS.
// INSTRUMENTED: iters loop, laundered pointers, idempotent stores.
__global__ __launch_bounds__(1024)
void weights_kernel(const float* __restrict__ scores,
                    const float* __restrict__ ctrl,
                    const float* __restrict__ bias,
                    float* __restrict__ rd, int iters) {
  const int bh = blockIdx.x;
  const int b = bh >> 3, h = bh & 7;
  const int t = threadIdx.x;

  __shared__ float buf[CELLS];   // 64 KB

  const float* cb = ctrl + b * CTRL;
  const float beta  = softplusf(cb[1024 + h]);
  const float gate  = 1.f / (1.f + expf(-cb[1032 + h]));
  float s0 = cb[1040 + h * 3 + 0];
  float s1 = cb[1040 + h * 3 + 1];
  float s2 = cb[1040 + h * 3 + 2];
  {
    float sm = fmaxf(s0, fmaxf(s1, s2));
    float e0 = expf(s0 - sm), e1 = expf(s1 - sm), e2 = expf(s2 - sm);
    float inv = 1.f / (e0 + e1 + e2);
    s0 = e0 * inv; s1 = e1 * inv; s2 = e2 * inv;
  }
  const float gamma = 1.f + softplusf(cb[1064 + h]);

  for (int it = 0; it < iters; ++it) {
    const float* srow = scores + (size_t)bh * CELLS;
    const float* brow = bias + (size_t)h * CELLS;
    float* rrow = rd + (size_t)bh * CELLS;
    asm volatile("" : "+v"(srow), "+v"(brow), "+v"(rrow));

    // --- content softmax: x = scores*beta ---
    float x[16];
    #pragma unroll
    for (int i = 0; i < 16; ++i) x[i] = srow[t + i * 1024] * beta;
    float mx = x[0];
    #pragma unroll
    for (int i = 1; i < 16; ++i) mx = fmaxf(mx, x[i]);
    mx = block_reduce<1>(mx, buf);
    float se = 0.f;
    #pragma unroll
    for (int i = 0; i < 16; ++i) { x[i] = expf(x[i] - mx); se += x[i]; }
    se = block_reduce<0>(se, buf);

    // --- prev-weights softmax of bias row ---
    float y[16];
    #pragma unroll
    for (int i = 0; i < 16; ++i) y[i] = brow[t + i * 1024];
    float mb = y[0];
    #pragma unroll
    for (int i = 1; i < 16; ++i) mb = fmaxf(mb, y[i]);
    mb = block_reduce<1>(mb, buf);
    float sb = 0.f;
    #pragma unroll
    for (int i = 0; i < 16; ++i) { y[i] = expf(y[i] - mb); sb += y[i]; }
    sb = block_reduce<0>(sb, buf);

    // --- interpolate into LDS ---
    const float a1 = gate / se;
    const float a2 = (1.f - gate) / sb;
    #pragma unroll
    for (int i = 0; i < 16; ++i)
      buf[t + i * 1024] = a1 * x[i] + a2 * y[i];
    __syncthreads();

    // --- circular shift + sharpen ---
    float sh[16]; float ss = 0.f;
    #pragma unroll
    for (int i = 0; i < 16; ++i) {
      int c = t + i * 1024;
      float wm = buf[(c + CELLS - 1) & (CELLS - 1)];
      float w0 = buf[c];
      float wp = buf[(c + 1) & (CELLS - 1)];
      float ws = fmaf(s0, wm, fmaf(s1, w0, s2 * wp));
      float p = powf(ws, gamma);
      sh[i] = p; ss += p;
    }
    ss = block_reduce<0>(ss, buf);   // leading barrier protects neighbor reads
    const float inv = 1.f / (ss + 1e-8f);
    #pragma unroll
    for (int i = 0; i < 16; ++i) rrow[t + i * 1024] = sh[i] * inv;
  }
}

// ---------------- Kernel 3: weighted read ----------------
// grid (CELLS/CB, BATCH), block 256.
// INSTRUMENTED: iters loop; first iters-1 passes atomicAdd into dummy
// (same contention pattern, never read) so the final result is exact.
__global__ __launch_bounds__(256)
void read_kernel(const float* __restrict__ mem,
                 const float* __restrict__ rd,
                 float* __restrict__ out,
                 float* __restrict__ dummy, int iters) {
  const int b  = blockIdx.y;
  const int c0 = blockIdx.x * CB;
  const int t  = threadIdx.x;

  __shared__ float rds[HEADS][CB];           // 8 KB
  __shared__ float red[8][HEADS * WORD];     // 32 KB

  for (int it = 0; it < iters; ++it) {
    const float* mb2 = mem;
    const float* rb  = rd;
    float* ob = (it == iters - 1) ? out : dummy;
    asm volatile("" : "+v"(mb2), "+v"(rb), "+v"(ob));

    __syncthreads();   // WAR: previous iteration's red reads must finish
    for (int i = t; i < HEADS * CB; i += 256)
      rds[i >> 8][i & 255] = rb[((size_t)b * HEADS + (i >> 8)) * CELLS + c0 + (i & 255)];
    __syncthreads();

    const int w4 = (t & 31) * 4;
    const int cc = t >> 5;
    float4 acc[HEADS];
    #pragma unroll
    for (int h = 0; h < HEADS; ++h) acc[h] = make_float4(0.f, 0.f, 0.f, 0.f);

    for (int c = cc; c < CB; c += 8) {
      float4 m = *(const float4*)&mb2[((size_t)b * CELLS + c0 + c) * WORD + w4];
      #pragma unroll
      for (int h = 0; h < HEADS; ++h) {
        float r = rds[h][c];
        acc[h].x = fmaf(r, m.x, acc[h].x);
        acc[h].y = fmaf(r, m.y, acc[h].y);
        acc[h].z = fmaf(r, m.z, acc[h].z);
        acc[h].w = fmaf(r, m.w, acc[h].w);
      }
    }

    #pragma unroll
    for (int h = 0; h < HEADS; ++h)
      *(float4*)&red[cc][h * WORD + w4] = acc[h];
    __syncthreads();

    float4 s = *(float4*)&red[0][t * 4];
    #pragma unroll
    for (int c2 = 1; c2 < 8; ++c2) {
      float4 v = *(float4*)&red[c2][t * 4];
      s.x += v.x; s.y += v.y; s.z += v.z; s.w += v.w;
    }
    const int h = t >> 5;
    const int w = (t * 4) & 127;
    float* o = &ob[((size_t)b * HEADS + h) * WORD + w];
    atomicAdd(o + 0, s.x);
    atomicAdd(o + 1, s.y);
    atomicAdd(o + 2, s.z);
    atomicAdd(o + 3, s.w);
  }
}

extern "C" void kernel_launch(void* const* d_in, const int* in_sizes, int n_in,
                              void* d_out, int out_size, void* d_ws, size_t ws_size,
                              hipStream_t stream) {
  const float* mem  = (const float*)d_in[0];
  const float* ctrl = (const float*)d_in[1];
  const float* bias = (const float*)d_in[2];
  float* out    = (float*)d_out;
  float* scores = (float*)d_ws;                              // 8 MB
  float* rd     = scores + (size_t)BATCH * HEADS * CELLS;    // 8 MB
  float* dummy  = rd + (size_t)BATCH * HEADS * CELLS;        // 16 KB sink

  hipMemsetAsync(d_out, 0, sizeof(float) * BATCH * HEADS * WORD, stream);

  // k1: rewritten (coalesced). k2/k3: amplified x10 for per-kernel counters.
  scores_kernel<<<dim3(CELLS / 128, BATCH), 256, 0, stream>>>(mem, ctrl, scores);
  weights_kernel<<<dim3(BATCH * HEADS), 1024, 0, stream>>>(scores, ctrl, bias, rd, 10);
  read_kernel<<<dim3(CELLS / CB, BATCH), 256, 0, stream>>>(mem, rd, out, dummy, 10);
}

// Round 7
// 277.818 us; speedup vs baseline: 3.5721x; 2.6014x over previous
//
#include <hip/hip_runtime.h>

#define BATCH 16
#define HEADS 8
#define WORD  128
#define CELLS 16384
#define CTRL  1072      // HEADS*(WORD+6)
#define K1_TILE 128     // cells per block in scores kernel
#define CB    256       // cells per block in read kernel

__device__ __forceinline__ float softplusf(float x) {
  return (x > 20.f) ? x : log1pf(expf(x));
}

// fast pow for ws>0: 2^(g*log2(ws)) via raw hw ops (avoids glibc __exp2f clash)
__device__ __forceinline__ float powpos(float ws, float g) {
  return __builtin_amdgcn_exp2f(g * __builtin_amdgcn_logf(ws));
}

// OP: 0 = sum, 1 = max. scratch >= 16 floats.
template<int OP>
__device__ __forceinline__ float block_reduce(float v, float* scratch) {
  #pragma unroll
  for (int o = 32; o > 0; o >>= 1) {
    float u = __shfl_xor(v, o, 64);
    v = OP ? fmaxf(v, u) : (v + u);
  }
  const int t = threadIdx.x;
  __syncthreads();
  if ((t & 63) == 0) scratch[t >> 6] = v;
  __syncthreads();
  if (t < 64) {
    v = (t < (int)(blockDim.x >> 6)) ? scratch[t] : (OP ? -3.4e38f : 0.f);
    #pragma unroll
    for (int o = 8; o > 0; o >>= 1) {
      float u = __shfl_xor(v, o, 64);
      v = OP ? fmaxf(v, u) : (v + u);
    }
    if (t == 0) scratch[0] = v;
  }
  __syncthreads();
  v = scratch[0];
  __syncthreads();
  return v;
}

// ---------------- Kernel 0: bias softmax (b-independent, once per head) ----
// grid HEADS, block 1024. pw[h][c] = softmax(bias[h])[c]
__global__ __launch_bounds__(1024)
void bias_softmax_kernel(const float* __restrict__ bias, float* __restrict__ pw) {
  __shared__ float red[16];
  const int h = blockIdx.x, t = threadIdx.x;
  const float4* b4 = (const float4*)(bias + (size_t)h * CELLS);
  float4* p4 = (float4*)(pw + (size_t)h * CELLS);

  float y[16];
  #pragma unroll
  for (int i4 = 0; i4 < 4; ++i4) {
    float4 v = b4[t * 4 + i4];
    y[i4*4+0] = v.x; y[i4*4+1] = v.y; y[i4*4+2] = v.z; y[i4*4+3] = v.w;
  }
  float m = y[0];
  #pragma unroll
  for (int i = 1; i < 16; ++i) m = fmaxf(m, y[i]);
  m = block_reduce<1>(m, red);
  float s = 0.f;
  #pragma unroll
  for (int i = 0; i < 16; ++i) {
    y[i] = __builtin_amdgcn_exp2f((y[i] - m) * 1.442695040888963f);
    s += y[i];
  }
  s = block_reduce<0>(s, red);
  const float inv = 1.f / s;
  #pragma unroll
  for (int i4 = 0; i4 < 4; ++i4)
    p4[t * 4 + i4] = make_float4(y[i4*4+0]*inv, y[i4*4+1]*inv,
                                 y[i4*4+2]*inv, y[i4*4+3]*inv);
}

// ---------------- Kernel 1: cosine-similarity scores (LDS-staged) ----------
// grid (CELLS/K1_TILE, BATCH), block 256 (4 waves).
// Stage: coalesced float4 loads (consecutive lanes -> consecutive 16B; every
// cache line fully consumed by one instruction -> zero live-line pressure),
// XOR-swizzled into a 64KB LDS tile. Compute: 4 lanes per cell, each covering
// f4 cols {q, q+4, ..., q+28}; keys via near-broadcast LDS reads; 2-stage
// shfl_xor butterfly (all 4 quad lanes end with full sums); 2 heads/lane store.
__global__ __launch_bounds__(256)
void scores_kernel(const float* __restrict__ mem,
                   const float* __restrict__ ctrl,
                   float* __restrict__ scores) {
  const int b = blockIdx.y;
  const int t = threadIdx.x;

  __shared__ __align__(16) float kk[HEADS * WORD];      // 4 KB tanh(keys)
  __shared__ float kn[HEADS];
  __shared__ __align__(16) float tile[K1_TILE * WORD];  // 64 KB

  for (int i = t; i < HEADS * WORD; i += 256)
    kk[i] = tanhf(ctrl[b * CTRL + i]);
  __syncthreads();
  if (t < HEADS) {
    float s = 0.f;
    for (int w = 0; w < WORD; ++w) { float v = kk[t * WORD + w]; s += v * v; }
    kn[t] = sqrtf(s);          // consumed after the stage barrier below
  }

  // ---- stage 64 KB tile, swizzled: tile4[r*32 + (c ^ (r&7))] = g[r][c]
  float4* tile4 = (float4*)tile;
  const float4* gt4 =
      (const float4*)(mem + ((size_t)b * CELLS + (size_t)blockIdx.x * K1_TILE) * WORD);
  float4 stg[16];
  #pragma unroll
  for (int j = 0; j < 16; ++j) stg[j] = gt4[j * 256 + t];   // 16 independent 1KB/wave loads
  #pragma unroll
  for (int j = 0; j < 16; ++j) {
    int i = j * 256 + t;
    int r = i >> 5, c = i & 31;
    tile4[r * 32 + (c ^ (r & 7))] = stg[j];
  }
  __syncthreads();

  // ---- compute: quad = cell-in-pass, q = word-quarter
  const float4* kk4 = (const float4*)kk;
  const int quad = t >> 2, q = t & 3;
  const size_t srow0 = (size_t)b * HEADS * CELLS + (size_t)blockIdx.x * K1_TILE;

  #pragma unroll
  for (int p = 0; p < 2; ++p) {
    const int cell = p * 64 + quad;
    float d[HEADS];
    #pragma unroll
    for (int h = 0; h < HEADS; ++h) d[h] = 0.f;
    float nm = 0.f;

    #pragma unroll
    for (int jj = 0; jj < 8; ++jj) {
      const int j = jj * 4 + q;                       // logical f4 col
      float4 m = tile4[cell * 32 + (j ^ (cell & 7))];
      nm = fmaf(m.x, m.x, fmaf(m.y, m.y, fmaf(m.z, m.z, fmaf(m.w, m.w, nm))));
      #pragma unroll
      for (int h = 0; h < HEADS; ++h) {
        float4 k = kk4[h * 32 + j];
        d[h] = fmaf(m.x, k.x, fmaf(m.y, k.y, fmaf(m.z, k.z, fmaf(m.w, k.w, d[h]))));
      }
    }
    // 2-stage butterfly within the quad: all 4 lanes get full sums
    #pragma unroll
    for (int off = 1; off <= 2; off <<= 1) {
      #pragma unroll
      for (int h = 0; h < HEADS; ++h) d[h] += __shfl_xor(d[h], off);
      nm += __shfl_xor(nm, off);
    }
    const float nmr = sqrtf(nm);
    #pragma unroll
    for (int u = 0; u < 2; ++u) {
      const int h = q * 2 + u;
      scores[srow0 + (size_t)h * CELLS + cell] = d[h] / (kn[h] * nmr + 1e-8f);
    }
  }
}

// ---------------- Kernel 2: softmax / interp / shift / sharpen -------------
// grid (BATCH*HEADS), block 1024. Thread owns cells [t*16, t*16+16): float4
// global I/O, conv neighbors in-register except thread edges (8KB LDS).
__global__ __launch_bounds__(1024)
void weights_kernel(const float* __restrict__ scores,
                    const float* __restrict__ ctrl,
                    const float* __restrict__ pw,
                    float* __restrict__ rd) {
  const int bh = blockIdx.x;
  const int b = bh >> 3, h = bh & 7;
  const int t = threadIdx.x;

  __shared__ float red[16];
  __shared__ float wl[1024], wr[1024];   // per-thread edge w_interp values

  const float* cb = ctrl + b * CTRL;
  const float beta  = softplusf(cb[1024 + h]);
  const float gate  = 1.f / (1.f + expf(-cb[1032 + h]));
  float s0 = cb[1040 + h * 3 + 0];
  float s1 = cb[1040 + h * 3 + 1];
  float s2 = cb[1040 + h * 3 + 2];
  {
    float sm = fmaxf(s0, fmaxf(s1, s2));
    float e0 = expf(s0 - sm), e1 = expf(s1 - sm), e2 = expf(s2 - sm);
    float inv = 1.f / (e0 + e1 + e2);
    s0 = e0 * inv; s1 = e1 * inv; s2 = e2 * inv;
  }
  const float gamma = 1.f + softplusf(cb[1064 + h]);

  // --- content softmax over this (b,h) row ---
  const float4* s4 = (const float4*)(scores + (size_t)bh * CELLS);
  float x[16];
  #pragma unroll
  for (int i4 = 0; i4 < 4; ++i4) {
    float4 v = s4[t * 4 + i4];
    x[i4*4+0] = v.x * beta; x[i4*4+1] = v.y * beta;
    x[i4*4+2] = v.z * beta; x[i4*4+3] = v.w * beta;
  }
  float mx = x[0];
  #pragma unroll
  for (int i = 1; i < 16; ++i) mx = fmaxf(mx, x[i]);
  mx = block_reduce<1>(mx, red);
  float se = 0.f;
  #pragma unroll
  for (int i = 0; i < 16; ++i) {
    x[i] = __builtin_amdgcn_exp2f((x[i] - mx) * 1.442695040888963f);
    se += x[i];
  }
  se = block_reduce<0>(se, red);

  // --- interpolate with precomputed prev-weights ---
  const float4* p4 = (const float4*)(pw + (size_t)h * CELLS);
  const float a1 = gate / se;
  const float a2 = 1.f - gate;
  float wi[16];
  #pragma unroll
  for (int i4 = 0; i4 < 4; ++i4) {
    float4 v = p4[t * 4 + i4];
    wi[i4*4+0] = fmaf(a1, x[i4*4+0], a2 * v.x);
    wi[i4*4+1] = fmaf(a1, x[i4*4+1], a2 * v.y);
    wi[i4*4+2] = fmaf(a1, x[i4*4+2], a2 * v.z);
    wi[i4*4+3] = fmaf(a1, x[i4*4+3], a2 * v.w);
  }
  wl[t] = wi[0]; wr[t] = wi[15];
  __syncthreads();

  // --- circular conv + sharpen (pow via hw log2/exp2; ws > 0 always) ---
  const float wmE = wr[(t + 1023) & 1023];   // w_interp[c-1] at i==0 (circular)
  const float wpE = wl[(t + 1)    & 1023];   // w_interp[c+1] at i==15 (circular)
  float sh[16]; float ss = 0.f;
  #pragma unroll
  for (int i = 0; i < 16; ++i) {
    float wm = (i == 0)  ? wmE : wi[i - 1];
    float wp = (i == 15) ? wpE : wi[i + 1];
    float ws = fmaf(s0, wm, fmaf(s1, wi[i], s2 * wp));
    float p = powpos(ws, gamma);
    sh[i] = p; ss += p;
  }
  ss = block_reduce<0>(ss, red);
  const float inv = 1.f / (ss + 1e-8f);
  float4* r4 = (float4*)(rd + (size_t)bh * CELLS);
  #pragma unroll
  for (int i4 = 0; i4 < 4; ++i4)
    r4[t * 4 + i4] = make_float4(sh[i4*4+0]*inv, sh[i4*4+1]*inv,
                                 sh[i4*4+2]*inv, sh[i4*4+3]*inv);
}

// ---------------- Kernel 3: weighted read ----------------------------------
// grid (CELLS/CB, BATCH), block 256. Loads already coalesced (1KB/wave-instr).
__global__ __launch_bounds__(256)
void read_kernel(const float* __restrict__ mem,
                 const float* __restrict__ rd,
                 float* __restrict__ out) {
  const int b  = blockIdx.y;
  const int c0 = blockIdx.x * CB;
  const int t  = threadIdx.x;

  __shared__ float rds[HEADS][CB];           // 8 KB
  __shared__ float red[8][HEADS * WORD];     // 32 KB

  for (int i = t; i < HEADS * CB; i += 256)
    rds[i >> 8][i & 255] = rd[((size_t)b * HEADS + (i >> 8)) * CELLS + c0 + (i & 255)];
  __syncthreads();

  const int w4 = (t & 31) * 4;
  const int cc = t >> 5;
  float4 acc[HEADS];
  #pragma unroll
  for (int h = 0; h < HEADS; ++h) acc[h] = make_float4(0.f, 0.f, 0.f, 0.f);

  for (int c = cc; c < CB; c += 8) {
    float4 m = *(const float4*)&mem[((size_t)b * CELLS + c0 + c) * WORD + w4];
    #pragma unroll
    for (int h = 0; h < HEADS; ++h) {
      float r = rds[h][c];
      acc[h].x = fmaf(r, m.x, acc[h].x);
      acc[h].y = fmaf(r, m.y, acc[h].y);
      acc[h].z = fmaf(r, m.z, acc[h].z);
      acc[h].w = fmaf(r, m.w, acc[h].w);
    }
  }

  #pragma unroll
  for (int h = 0; h < HEADS; ++h)
    *(float4*)&red[cc][h * WORD + w4] = acc[h];
  __syncthreads();

  float4 s = *(float4*)&red[0][t * 4];
  #pragma unroll
  for (int c2 = 1; c2 < 8; ++c2) {
    float4 v = *(float4*)&red[c2][t * 4];
    s.x += v.x; s.y += v.y; s.z += v.z; s.w += v.w;
  }
  const int h = t >> 5;
  const int w = (t * 4) & 127;
  float* o = &out[((size_t)b * HEADS + h) * WORD + w];
  atomicAdd(o + 0, s.x);
  atomicAdd(o + 1, s.y);
  atomicAdd(o + 2, s.z);
  atomicAdd(o + 3, s.w);
}

extern "C" void kernel_launch(void* const* d_in, const int* in_sizes, int n_in,
                              void* d_out, int out_size, void* d_ws, size_t ws_size,
                              hipStream_t stream) {
  const float* mem  = (const float*)d_in[0];
  const float* ctrl = (const float*)d_in[1];
  const float* bias = (const float*)d_in[2];
  float* out    = (float*)d_out;
  float* scores = (float*)d_ws;                              // 8 MB
  float* rd     = scores + (size_t)BATCH * HEADS * CELLS;    // 8 MB
  float* pw     = rd + (size_t)BATCH * HEADS * CELLS;        // 512 KB

  (void)hipMemsetAsync(d_out, 0, sizeof(float) * BATCH * HEADS * WORD, stream);

  bias_softmax_kernel<<<dim3(HEADS), 1024, 0, stream>>>(bias, pw);
  scores_kernel<<<dim3(CELLS / K1_TILE, BATCH), 256, 0, stream>>>(mem, ctrl, scores);
  weights_kernel<<<dim3(BATCH * HEADS), 1024, 0, stream>>>(scores, ctrl, pw, rd);
  read_kernel<<<dim3(CELLS / CB, BATCH), 256, 0, stream>>>(mem, rd, out);
}

// Round 10
// 271.158 us; speedup vs baseline: 3.6599x; 1.0246x over previous
//
#include <hip/hip_runtime.h>

#define BATCH 16
#define HEADS 8
#define WORD  128
#define CELLS 16384
#define CTRL  1072      // HEADS*(WORD+6)
#define CB    256       // cells per block in read kernel

__device__ __forceinline__ float softplusf(float x) {
  return (x > 20.f) ? x : log1pf(expf(x));
}

// fast pow for ws>0: 2^(g*log2(ws)) via raw hw ops (avoids glibc __exp2f clash)
__device__ __forceinline__ float powpos(float ws, float g) {
  return __builtin_amdgcn_exp2f(g * __builtin_amdgcn_logf(ws));
}

// OP: 0 = sum, 1 = max. scratch >= 16 floats.
template<int OP>
__device__ __forceinline__ float block_reduce(float v, float* scratch) {
  #pragma unroll
  for (int o = 32; o > 0; o >>= 1) {
    float u = __shfl_xor(v, o, 64);
    v = OP ? fmaxf(v, u) : (v + u);
  }
  const int t = threadIdx.x;
  __syncthreads();
  if ((t & 63) == 0) scratch[t >> 6] = v;
  __syncthreads();
  if (t < 64) {
    v = (t < (int)(blockDim.x >> 6)) ? scratch[t] : (OP ? -3.4e38f : 0.f);
    #pragma unroll
    for (int o = 8; o > 0; o >>= 1) {
      float u = __shfl_xor(v, o, 64);
      v = OP ? fmaxf(v, u) : (v + u);
    }
    if (t == 0) scratch[0] = v;
  }
  __syncthreads();
  v = scratch[0];
  __syncthreads();
  return v;
}

// ---------------- Kernel 0: bias softmax (b-independent, once per head) ----
__global__ __launch_bounds__(1024)
void bias_softmax_kernel(const float* __restrict__ bias, float* __restrict__ pw) {
  __shared__ float red[16];
  const int h = blockIdx.x, t = threadIdx.x;
  const float4* b4 = (const float4*)(bias + (size_t)h * CELLS);
  float4* p4 = (float4*)(pw + (size_t)h * CELLS);

  float y[16];
  #pragma unroll
  for (int i4 = 0; i4 < 4; ++i4) {
    float4 v = b4[t * 4 + i4];
    y[i4*4+0] = v.x; y[i4*4+1] = v.y; y[i4*4+2] = v.z; y[i4*4+3] = v.w;
  }
  float m = y[0];
  #pragma unroll
  for (int i = 1; i < 16; ++i) m = fmaxf(m, y[i]);
  m = block_reduce<1>(m, red);
  float s = 0.f;
  #pragma unroll
  for (int i = 0; i < 16; ++i) {
    y[i] = __builtin_amdgcn_exp2f((y[i] - m) * 1.442695040888963f);
    s += y[i];
  }
  s = block_reduce<0>(s, red);
  const float inv = 1.f / s;
  #pragma unroll
  for (int i4 = 0; i4 < 4; ++i4)
    p4[t * 4 + i4] = make_float4(y[i4*4+0]*inv, y[i4*4+1]*inv,
                                 y[i4*4+2]*inv, y[i4*4+3]*inv);
}

// ---------------- Kernel 1: cosine-similarity scores (streaming butterfly) --
// grid (64, BATCH), block 256 (4 waves), ~4 KB LDS -> high occupancy.
// Per wave-load: 64 lanes x float4 = 1 KB = rows {2p, 2p+1} fully consumed
// (perfect coalescing, no live-line pressure). Keys hoisted to 32 VGPRs.
// Reduction: 5-stage shfl_xor butterfly per 32-lane half (offsets <=16 never
// cross halves). 2-deep register pipeline: prefetch next 4 pairs while
// reducing current 4 -> loads stay outstanding under compute.
__global__ __launch_bounds__(256, 4)
void scores_kernel(const float* __restrict__ mem,
                   const float* __restrict__ ctrl,
                   float* __restrict__ scores) {
  const int b  = blockIdx.y;
  const int t  = threadIdx.x;
  const int wv = t >> 6;
  const int l  = t & 63;
  const int half = l >> 5;
  const int li   = l & 31;

  __shared__ __align__(16) float kk[HEADS * WORD];   // tanh(keys)
  __shared__ float kn[HEADS];

  for (int i = t; i < HEADS * WORD; i += 256)
    kk[i] = tanhf(ctrl[b * CTRL + i]);
  __syncthreads();
  if (t < HEADS) {
    float s = 0.f;
    for (int w = 0; w < WORD; ++w) { float v = kk[t * WORD + w]; s += v * v; }
    kn[t] = sqrtf(s);
  }
  __syncthreads();

  float4 kreg[HEADS];
  #pragma unroll
  for (int h = 0; h < HEADS; ++h)
    kreg[h] = *(const float4*)&kk[h * WORD + li * 4];
  const float knl = kn[li & 7];          // valid for writer lanes (li<8)

  const float4* mb = (const float4*)(mem + (size_t)b * CELLS * WORD);
  float* srow = scores + (size_t)b * HEADS * CELLS;

  // wave's contiguous run: 32 row-pairs, in 8 chunks of 4
  const int gw = blockIdx.x * 4 + wv;    // 0..255 within this b
  const int p0 = gw * 32;

  float4 cur[4], nxt[4];
  #pragma unroll
  for (int i = 0; i < 4; ++i)
    cur[i] = mb[(size_t)(2 * (p0 + i) + half) * 32 + li];

  for (int c = 0; c < 8; ++c) {
    const int pc = (c < 7) ? (c + 1) : 7;        // last prefetch = redundant reload
    #pragma unroll
    for (int i = 0; i < 4; ++i)
      nxt[i] = mb[(size_t)(2 * (p0 + pc * 4 + i) + half) * 32 + li];

    #pragma unroll
    for (int i = 0; i < 4; ++i) {
      const float4 m = cur[i];
      float nm = fmaf(m.x, m.x, fmaf(m.y, m.y, fmaf(m.z, m.z, m.w * m.w)));
      float d[HEADS];
      #pragma unroll
      for (int h = 0; h < HEADS; ++h)
        d[h] = fmaf(m.x, kreg[h].x, fmaf(m.y, kreg[h].y,
               fmaf(m.z, kreg[h].z, m.w * kreg[h].w)));
      #pragma unroll
      for (int off = 1; off <= 16; off <<= 1) {
        #pragma unroll
        for (int h = 0; h < HEADS; ++h) d[h] += __shfl_xor(d[h], off);
        nm += __shfl_xor(nm, off);
      }
      if (li < HEADS) {
        const float nmr = sqrtf(nm);
        float dsel = d[0];
        #pragma unroll
        for (int h = 1; h < HEADS; ++h) dsel = (li == h) ? d[h] : dsel;
        const int row = 2 * (p0 + c * 4 + i) + half;
        srow[(size_t)li * CELLS + row] = dsel / (knl * nmr + 1e-8f);
      }
    }
    #pragma unroll
    for (int i = 0; i < 4; ++i) cur[i] = nxt[i];
  }
}

// ---------------- Kernel 2: softmax / interp / shift / sharpen -------------
// grid (BATCH*HEADS), block 1024. Thread owns cells [t*16, t*16+16).
__global__ __launch_bounds__(1024)
void weights_kernel(const float* __restrict__ scores,
                    const float* __restrict__ ctrl,
                    const float* __restrict__ pw,
                    float* __restrict__ rd) {
  const int bh = blockIdx.x;
  const int b = bh >> 3, h = bh & 7;
  const int t = threadIdx.x;

  __shared__ float red[16];
  __shared__ float wl[1024], wr[1024];   // per-thread edge w_interp values

  const float* cb = ctrl + b * CTRL;
  const float beta  = softplusf(cb[1024 + h]);
  const float gate  = 1.f / (1.f + expf(-cb[1032 + h]));
  float s0 = cb[1040 + h * 3 + 0];
  float s1 = cb[1040 + h * 3 + 1];
  float s2 = cb[1040 + h * 3 + 2];
  {
    float sm = fmaxf(s0, fmaxf(s1, s2));
    float e0 = expf(s0 - sm), e1 = expf(s1 - sm), e2 = expf(s2 - sm);
    float inv = 1.f / (e0 + e1 + e2);
    s0 = e0 * inv; s1 = e1 * inv; s2 = e2 * inv;
  }
  const float gamma = 1.f + softplusf(cb[1064 + h]);

  // --- content softmax over this (b,h) row ---
  const float4* s4 = (const float4*)(scores + (size_t)bh * CELLS);
  float x[16];
  #pragma unroll
  for (int i4 = 0; i4 < 4; ++i4) {
    float4 v = s4[t * 4 + i4];
    x[i4*4+0] = v.x * beta; x[i4*4+1] = v.y * beta;
    x[i4*4+2] = v.z * beta; x[i4*4+3] = v.w * beta;
  }
  float mx = x[0];
  #pragma unroll
  for (int i = 1; i < 16; ++i) mx = fmaxf(mx, x[i]);
  mx = block_reduce<1>(mx, red);
  float se = 0.f;
  #pragma unroll
  for (int i = 0; i < 16; ++i) {
    x[i] = __builtin_amdgcn_exp2f((x[i] - mx) * 1.442695040888963f);
    se += x[i];
  }
  se = block_reduce<0>(se, red);

  // --- interpolate with precomputed prev-weights ---
  const float4* p4 = (const float4*)(pw + (size_t)h * CELLS);
  const float a1 = gate / se;
  const float a2 = 1.f - gate;
  float wi[16];
  #pragma unroll
  for (int i4 = 0; i4 < 4; ++i4) {
    float4 v = p4[t * 4 + i4];
    wi[i4*4+0] = fmaf(a1, x[i4*4+0], a2 * v.x);
    wi[i4*4+1] = fmaf(a1, x[i4*4+1], a2 * v.y);
    wi[i4*4+2] = fmaf(a1, x[i4*4+2], a2 * v.z);
    wi[i4*4+3] = fmaf(a1, x[i4*4+3], a2 * v.w);
  }
  wl[t] = wi[0]; wr[t] = wi[15];
  __syncthreads();

  // --- circular conv + sharpen ---
  const float wmE = wr[(t + 1023) & 1023];
  const float wpE = wl[(t + 1)    & 1023];
  float sh[16]; float ss = 0.f;
  #pragma unroll
  for (int i = 0; i < 16; ++i) {
    float wm = (i == 0)  ? wmE : wi[i - 1];
    float wp = (i == 15) ? wpE : wi[i + 1];
    float ws = fmaf(s0, wm, fmaf(s1, wi[i], s2 * wp));
    float p = powpos(ws, gamma);
    sh[i] = p; ss += p;
  }
  ss = block_reduce<0>(ss, red);
  const float inv = 1.f / (ss + 1e-8f);
  float4* r4 = (float4*)(rd + (size_t)bh * CELLS);
  #pragma unroll
  for (int i4 = 0; i4 < 4; ++i4)
    r4[t * 4 + i4] = make_float4(sh[i4*4+0]*inv, sh[i4*4+1]*inv,
                                 sh[i4*4+2]*inv, sh[i4*4+3]*inv);
}

// ---------------- Kernel 3: weighted read ----------------------------------
// grid (CELLS/CB, BATCH), block 256. Loads coalesced (1KB/wave-instr).
__global__ __launch_bounds__(256)
void read_kernel(const float* __restrict__ mem,
                 const float* __restrict__ rd,
                 float* __restrict__ out) {
  const int b  = blockIdx.y;
  const int c0 = blockIdx.x * CB;
  const int t  = threadIdx.x;

  __shared__ float rds[HEADS][CB];           // 8 KB
  __shared__ float red[8][HEADS * WORD];     // 32 KB

  for (int i = t; i < HEADS * CB; i += 256)
    rds[i >> 8][i & 255] = rd[((size_t)b * HEADS + (i >> 8)) * CELLS + c0 + (i & 255)];
  __syncthreads();

  const int w4 = (t & 31) * 4;
  const int cc = t >> 5;
  float4 acc[HEADS];
  #pragma unroll
  for (int h = 0; h < HEADS; ++h) acc[h] = make_float4(0.f, 0.f, 0.f, 0.f);

  for (int c = cc; c < CB; c += 8) {
    float4 m = *(const float4*)&mem[((size_t)b * CELLS + c0 + c) * WORD + w4];
    #pragma unroll
    for (int h = 0; h < HEADS; ++h) {
      float r = rds[h][c];
      acc[h].x = fmaf(r, m.x, acc[h].x);
      acc[h].y = fmaf(r, m.y, acc[h].y);
      acc[h].z = fmaf(r, m.z, acc[h].z);
      acc[h].w = fmaf(r, m.w, acc[h].w);
    }
  }

  #pragma unroll
  for (int h = 0; h < HEADS; ++h)
    *(float4*)&red[cc][h * WORD + w4] = acc[h];
  __syncthreads();

  float4 s = *(float4*)&red[0][t * 4];
  #pragma unroll
  for (int c2 = 1; c2 < 8; ++c2) {
    float4 v = *(float4*)&red[c2][t * 4];
    s.x += v.x; s.y += v.y; s.z += v.z; s.w += v.w;
  }
  const int h = t >> 5;
  const int w = (t * 4) & 127;
  float* o = &out[((size_t)b * HEADS + h) * WORD + w];
  atomicAdd(o + 0, s.x);
  atomicAdd(o + 1, s.y);
  atomicAdd(o + 2, s.z);
  atomicAdd(o + 3, s.w);
}

extern "C" void kernel_launch(void* const* d_in, const int* in_sizes, int n_in,
                              void* d_out, int out_size, void* d_ws, size_t ws_size,
                              hipStream_t stream) {
  const float* mem  = (const float*)d_in[0];
  const float* ctrl = (const float*)d_in[1];
  const float* bias = (const float*)d_in[2];
  float* out    = (float*)d_out;
  float* scores = (float*)d_ws;                              // 8 MB
  float* rd     = scores + (size_t)BATCH * HEADS * CELLS;    // 8 MB
  float* pw     = rd + (size_t)BATCH * HEADS * CELLS;        // 512 KB

  (void)hipMemsetAsync(d_out, 0, sizeof(float) * BATCH * HEADS * WORD, stream);

  bias_softmax_kernel<<<dim3(HEADS), 1024, 0, stream>>>(bias, pw);
  scores_kernel<<<dim3(64, BATCH), 256, 0, stream>>>(mem, ctrl, scores);
  weights_kernel<<<dim3(BATCH * HEADS), 1024, 0, stream>>>(scores, ctrl, pw, rd);
  read_kernel<<<dim3(CELLS / CB, BATCH), 256, 0, stream>>>(mem, rd, out);
}